// Round 1
// baseline (1309.176 us; speedup 1.0000x reference)
//
#include <hip/hip_runtime.h>
#include <hip/hip_bf16.h>

// Problem constants (reference setup_inputs)
#define NN   5000   // nodes
#define EDIM 64     // embedding dim
#define DINC 32     // DIN
#define BB   16     // batch
#define LAGN 12     // LAG
#define BC   512    // BB*DINC (flattened batch*channel cols of the big GEMMs)

// ---------------------------------------------------------------------------
// K1: A = relu(emb @ emb^T), [NN, NN] fp32, row-major stride NN.
// 64x64 tile per 256-thread block; K=64 single pass through LDS.
// ---------------------------------------------------------------------------
__global__ __launch_bounds__(256) void build_A_kernel(const float* __restrict__ emb,
                                                      float* __restrict__ A) {
  __shared__ float Er[64][EDIM + 1];
  __shared__ float Ec[64][EDIM + 1];
  const int row0 = blockIdx.y * 64, col0 = blockIdx.x * 64;
  const int tid = threadIdx.y * 16 + threadIdx.x;
  for (int i = tid; i < 1024; i += 256) {   // 64 rows x 16 float4
    const int r = i >> 4, d4 = (i & 15) << 2;
    const int gr = row0 + r, gc = col0 + r;
    float4 v = make_float4(0.f, 0.f, 0.f, 0.f);
    float4 w = make_float4(0.f, 0.f, 0.f, 0.f);
    if (gr < NN) v = *(const float4*)(emb + gr * EDIM + d4);
    if (gc < NN) w = *(const float4*)(emb + gc * EDIM + d4);
    Er[r][d4 + 0] = v.x; Er[r][d4 + 1] = v.y; Er[r][d4 + 2] = v.z; Er[r][d4 + 3] = v.w;
    Ec[r][d4 + 0] = w.x; Ec[r][d4 + 1] = w.y; Ec[r][d4 + 2] = w.z; Ec[r][d4 + 3] = w.w;
  }
  __syncthreads();
  const int ty = threadIdx.y, tx = threadIdx.x;
  float acc[4][4] = {};
  for (int d = 0; d < EDIM; ++d) {
    float a[4], b[4];
#pragma unroll
    for (int r = 0; r < 4; ++r) a[r] = Er[ty + r * 16][d];
#pragma unroll
    for (int c = 0; c < 4; ++c) b[c] = Ec[tx + c * 16][d];
#pragma unroll
    for (int r = 0; r < 4; ++r)
#pragma unroll
      for (int c = 0; c < 4; ++c) acc[r][c] = fmaf(a[r], b[c], acc[r][c]);
  }
#pragma unroll
  for (int r = 0; r < 4; ++r) {
    const int gr = row0 + ty + r * 16;
    if (gr >= NN) continue;
#pragma unroll
    for (int c = 0; c < 4; ++c) {
      const int gc = col0 + tx + c * 16;
      if (gc < NN) A[(size_t)gr * NN + gc] = fmaxf(acc[r][c], 0.f);
    }
  }
}

// ---------------------------------------------------------------------------
// K2: per-row max and sum(exp(a - max)). One block per row.
// ---------------------------------------------------------------------------
__global__ __launch_bounds__(256) void row_stats_kernel(const float* __restrict__ A,
                                                        float* __restrict__ rmax,
                                                        float* __restrict__ rsum) {
  const int n = blockIdx.x;
  const float* row = A + (size_t)n * NN;
  __shared__ float red[256];
  float m = 0.f;  // relu output >= 0, diagonal > 0
  for (int j = threadIdx.x; j < NN; j += 256) m = fmaxf(m, row[j]);
  red[threadIdx.x] = m; __syncthreads();
  for (int s = 128; s > 0; s >>= 1) {
    if (threadIdx.x < s) red[threadIdx.x] = fmaxf(red[threadIdx.x], red[threadIdx.x + s]);
    __syncthreads();
  }
  m = red[0]; __syncthreads();
  float sum = 0.f;
  for (int j = threadIdx.x; j < NN; j += 256) sum += __expf(row[j] - m);
  red[threadIdx.x] = sum; __syncthreads();
  for (int s = 128; s > 0; s >>= 1) {
    if (threadIdx.x < s) red[threadIdx.x] += red[threadIdx.x + s];
    __syncthreads();
  }
  if (threadIdx.x == 0) { rmax[n] = m; rsum[n] = red[0]; }
}

// ---------------------------------------------------------------------------
// K3: Xr[m, b*32+c] = x[b, m, c]  ([NN, 512] row-major)
// ---------------------------------------------------------------------------
__global__ __launch_bounds__(256) void transpose_x_kernel(const float* __restrict__ x,
                                                          float* __restrict__ Xr) {
  const int idx = blockIdx.x * 256 + threadIdx.x;
  if (idx >= NN * BC) return;
  const int m = idx / BC, t = idx - m * BC;
  const int b = t >> 5, c = t & 31;
  Xr[idx] = x[((size_t)b * NN + m) * DINC + c];
}

// ---------------------------------------------------------------------------
// K4/K5: C[m, j] = (1/rsum[m]) * sum_k exp(A[m,k]-rmax[m]) * Bm[k, j]
// M=K=NN, Ncols=BC. BM=BN=64, BK=16, 256 threads, 4x4 micro-tile.
// exp applied in the A-tile loader (each loader thread owns one row -> rmax
// loaded once); 1/rsum folded into the epilogue.
// ---------------------------------------------------------------------------
__global__ __launch_bounds__(256) void gemm_softmax_kernel(const float* __restrict__ A,
                                                           const float* __restrict__ rmax,
                                                           const float* __restrict__ rsum,
                                                           const float* __restrict__ Bm,
                                                           float* __restrict__ C) {
  __shared__ __align__(16) float As[16][64];  // [k][m]
  __shared__ __align__(16) float Bs[16][64];  // [k][n]
  const int row0 = blockIdx.y * 64, col0 = blockIdx.x * 64;
  const int tid = threadIdx.x;
  const int lar = tid >> 2;            // A-load row 0..63
  const int lac = (tid & 3) << 2;      // A-load k offset 0,4,8,12
  const int lbr = tid >> 4;            // B-load k 0..15
  const int lbc = (tid & 15) << 2;     // B-load col
  const int glar = row0 + lar;
  const float rmv = (glar < NN) ? rmax[glar] : 0.f;
  const int ty = tid >> 4, tx = tid & 15;
  float acc[4][4] = {};
  const int numK = (NN + 15) >> 4;  // 313
  for (int kt = 0; kt < numK; ++kt) {
    const int k0 = kt << 4;
    {  // A tile (NN%4==0 so float4-granular bound check is exact)
      const bool ok = (glar < NN) && (k0 + lac < NN);
      float4 v = make_float4(0.f, 0.f, 0.f, 0.f);
      if (ok) v = *(const float4*)(A + (size_t)glar * NN + k0 + lac);
      As[lac + 0][lar] = ok ? __expf(v.x - rmv) : 0.f;
      As[lac + 1][lar] = ok ? __expf(v.y - rmv) : 0.f;
      As[lac + 2][lar] = ok ? __expf(v.z - rmv) : 0.f;
      As[lac + 3][lar] = ok ? __expf(v.w - rmv) : 0.f;
    }
    {  // B tile
      const int gk = k0 + lbr;
      float4 v = make_float4(0.f, 0.f, 0.f, 0.f);
      if (gk < NN) v = *(const float4*)(Bm + (size_t)gk * BC + col0 + lbc);
      *(float4*)&Bs[lbr][lbc] = v;
    }
    __syncthreads();
#pragma unroll
    for (int kk = 0; kk < 16; ++kk) {
      const float4 a4 = *(const float4*)&As[kk][ty << 2];
      const float4 b4 = *(const float4*)&Bs[kk][tx << 2];
      const float a[4] = {a4.x, a4.y, a4.z, a4.w};
      const float b[4] = {b4.x, b4.y, b4.z, b4.w};
#pragma unroll
      for (int r = 0; r < 4; ++r)
#pragma unroll
        for (int c = 0; c < 4; ++c) acc[r][c] = fmaf(a[r], b[c], acc[r][c]);
    }
    __syncthreads();
  }
#pragma unroll
  for (int r = 0; r < 4; ++r) {
    const int gm = row0 + (ty << 2) + r;
    if (gm >= NN) continue;
    const float inv = 1.f / rsum[gm];
    float4 o;
    o.x = acc[r][0] * inv; o.y = acc[r][1] * inv;
    o.z = acc[r][2] * inv; o.w = acc[r][3] * inv;
    *(float4*)(C + (size_t)gm * BC + col0 + (tx << 2)) = o;
  }
}

// ---------------------------------------------------------------------------
// K6/K7/K8: C[M, Nc] = emb[M, 64] @ Bw[64, Nc]   (Nc in {3072, 512, 64})
// BM=32, BN=64, full K=64 in one LDS pass; 2x4 micro-tile per thread.
// ---------------------------------------------------------------------------
__global__ __launch_bounds__(256) void emb_gemm_kernel(const float* __restrict__ Ae,
                                                       const float* __restrict__ Bw,
                                                       float* __restrict__ C,
                                                       int M, int Nc) {
  __shared__ float Aet[EDIM][32];             // [d][m]
  __shared__ __align__(16) float Bs[EDIM][64];  // [d][n]
  const int row0 = blockIdx.y * 32, col0 = blockIdx.x * 64;
  const int tid = threadIdx.x;
  for (int i = tid; i < 512; i += 256) {   // 32 rows x 16 float4
    const int r = i >> 4, d4 = (i & 15) << 2;
    const int gm = row0 + r;
    float4 v = make_float4(0.f, 0.f, 0.f, 0.f);
    if (gm < M) v = *(const float4*)(Ae + (size_t)gm * EDIM + d4);
    Aet[d4 + 0][r] = v.x; Aet[d4 + 1][r] = v.y; Aet[d4 + 2][r] = v.z; Aet[d4 + 3][r] = v.w;
  }
  for (int i = tid; i < 1024; i += 256) {  // 64 rows x 16 float4
    const int br = i >> 4, bc = (i & 15) << 2;
    *(float4*)&Bs[br][bc] = *(const float4*)(Bw + (size_t)br * Nc + col0 + bc);
  }
  __syncthreads();
  const int ty = tid >> 4, tx = tid & 15;
  float acc[2][4] = {};
#pragma unroll 8
  for (int d = 0; d < EDIM; ++d) {
    const float a0 = Aet[d][ty * 2], a1 = Aet[d][ty * 2 + 1];
    const float4 b4 = *(const float4*)&Bs[d][tx << 2];
    acc[0][0] = fmaf(a0, b4.x, acc[0][0]); acc[0][1] = fmaf(a0, b4.y, acc[0][1]);
    acc[0][2] = fmaf(a0, b4.z, acc[0][2]); acc[0][3] = fmaf(a0, b4.w, acc[0][3]);
    acc[1][0] = fmaf(a1, b4.x, acc[1][0]); acc[1][1] = fmaf(a1, b4.y, acc[1][1]);
    acc[1][2] = fmaf(a1, b4.z, acc[1][2]); acc[1][3] = fmaf(a1, b4.w, acc[1][3]);
  }
#pragma unroll
  for (int r = 0; r < 2; ++r) {
    const int gm = row0 + ty * 2 + r;
    if (gm >= M) continue;
    float4 o;
    o.x = acc[r][0]; o.y = acc[r][1]; o.z = acc[r][2]; o.w = acc[r][3];
    *(float4*)(C + (size_t)gm * Nc + col0 + (tx << 2)) = o;
  }
}

// ---------------------------------------------------------------------------
// K9: xwc[b, n, i] = sum_t T[t] * x_window[b, t, n, i]
// ---------------------------------------------------------------------------
__global__ __launch_bounds__(256) void window_combine_kernel(const float* __restrict__ xw,
                                                             const float* __restrict__ T,
                                                             float* __restrict__ out) {
  const int idx = blockIdx.x * 256 + threadIdx.x;
  if (idx >= BB * NN * 16) return;
  const int b = idx / (NN * 16);
  const int rem = idx - b * (NN * 16);
  float acc = 0.f;
#pragma unroll
  for (int t = 0; t < LAGN; ++t)
    acc = fmaf(T[t], xw[(size_t)(b * LAGN + t) * (NN * 16) + rem], acc);
  out[idx] = acc;
}

// ---------------------------------------------------------------------------
// K10: per-node fusion: gconv (x,Y1,Y2 against W[n]), wconv (xwc against ww[n]),
// both LayerNorms (shfl reduce over the 32-lane o-group), concat + bias.
// One block per node; threads = (batch-group of 8) x (o=0..31), 2 reps.
// ---------------------------------------------------------------------------
__global__ __launch_bounds__(256) void fuse_out_kernel(const float* __restrict__ x,
                                                       const float* __restrict__ Y1,
                                                       const float* __restrict__ Y2,
                                                       const float* __restrict__ W,
                                                       const float* __restrict__ WWm,
                                                       const float* __restrict__ biasN,
                                                       const float* __restrict__ xwc,
                                                       const float* __restrict__ ln1w,
                                                       const float* __restrict__ ln1b,
                                                       const float* __restrict__ ln2w,
                                                       const float* __restrict__ ln2b,
                                                       float* __restrict__ out) {
  const int n = blockIdx.x;
  __shared__ __align__(16) float Wn[3072];
  __shared__ __align__(16) float WWn[512];
  __shared__ __align__(16) float x0v[512], y1v[512], y2v[512];
  __shared__ __align__(16) float xwv[256];
  __shared__ __align__(16) float bv[64];
  const int tid = threadIdx.x;
  for (int i = tid; i < 768; i += 256)
    *(float4*)&Wn[i << 2] = *(const float4*)(W + (size_t)n * 3072 + (i << 2));
  if (tid < 128) {
    *(float4*)&WWn[tid << 2] = *(const float4*)(WWm + (size_t)n * 512 + (tid << 2));
    *(float4*)&y1v[tid << 2] = *(const float4*)(Y1 + (size_t)n * 512 + (tid << 2));
    *(float4*)&y2v[tid << 2] = *(const float4*)(Y2 + (size_t)n * 512 + (tid << 2));
    const int b = tid >> 3, c4 = (tid & 7) << 2;
    *(float4*)&x0v[(b << 5) + c4] = *(const float4*)(x + ((size_t)b * NN + n) * DINC + c4);
  }
  if (tid < 64) {
    const int b = tid >> 2, i4 = (tid & 3) << 2;
    *(float4*)&xwv[(b << 4) + i4] = *(const float4*)(xwc + ((size_t)b * NN + n) * 16 + i4);
  }
  if (tid < 16)
    *(float4*)&bv[tid << 2] = *(const float4*)(biasN + (size_t)n * 64 + (tid << 2));
  __syncthreads();
  const int o = tid & 31, bg = tid >> 5;
  const float w1 = ln1w[o], b1 = ln1b[o], w2 = ln2w[o], b2 = ln2b[o];
  const float bvg = bv[o], bvw = bv[32 + o];
#pragma unroll
  for (int rep = 0; rep < 2; ++rep) {
    const int b = bg + (rep << 3);
    float gv = 0.f;
#pragma unroll
    for (int i = 0; i < 32; ++i) gv = fmaf(x0v[(b << 5) + i], Wn[i * 32 + o], gv);
#pragma unroll
    for (int i = 0; i < 32; ++i) gv = fmaf(y1v[(b << 5) + i], Wn[1024 + i * 32 + o], gv);
#pragma unroll
    for (int i = 0; i < 32; ++i) gv = fmaf(y2v[(b << 5) + i], Wn[2048 + i * 32 + o], gv);
    float wv = 0.f;
#pragma unroll
    for (int i = 0; i < 16; ++i) wv = fmaf(xwv[(b << 4) + i], WWn[i * 32 + o], wv);
    // LN over the 32 o-lanes (aligned 32-lane subgroup of the wave)
    float s1 = gv, s2 = gv * gv;
#pragma unroll
    for (int m = 16; m >= 1; m >>= 1) { s1 += __shfl_xor(s1, m, 32); s2 += __shfl_xor(s2, m, 32); }
    const float mu = s1 * 0.03125f;
    const float var = s2 * 0.03125f - mu * mu;
    const float og = (gv - mu) * rsqrtf(var + 1e-5f) * w1 + b1 + bvg;
    float t1 = wv, t2 = wv * wv;
#pragma unroll
    for (int m = 16; m >= 1; m >>= 1) { t1 += __shfl_xor(t1, m, 32); t2 += __shfl_xor(t2, m, 32); }
    const float mu2 = t1 * 0.03125f;
    const float var2 = t2 * 0.03125f - mu2 * mu2;
    const float ow = (wv - mu2) * rsqrtf(var2 + 1e-5f) * w2 + b2 + bvw;
    float* op = out + ((size_t)b * NN + n) * 64;
    op[o] = og;
    op[32 + o] = ow;
  }
}

// ---------------------------------------------------------------------------
// Workspace layout (fp32 elements). Total 32,690,240 floats = 130.8 MB.
// W/WW/biasN/xwc OVERLAY the A region — they are written only after both
// softmax GEMMs (stream-ordered) have finished reading A.
// ---------------------------------------------------------------------------
extern "C" void kernel_launch(void* const* d_in, const int* in_sizes, int n_in,
                              void* d_out, int out_size, void* d_ws, size_t ws_size,
                              hipStream_t stream) {
  const float* x     = (const float*)d_in[0];
  const float* xwin  = (const float*)d_in[1];
  const float* emb   = (const float*)d_in[2];
  const float* wpool = (const float*)d_in[3];
  const float* wwin  = (const float*)d_in[4];
  const float* bpool = (const float*)d_in[5];
  const float* T     = (const float*)d_in[6];
  const float* ln1w  = (const float*)d_in[7];
  const float* ln1b  = (const float*)d_in[8];
  const float* ln2w  = (const float*)d_in[9];
  const float* ln2b  = (const float*)d_in[10];
  float* out = (float*)d_out;
  float* ws = (float*)d_ws;

  float* A     = ws;              // 25,000,000
  float* Wm    = ws;              // 15,360,000  (overlays A)
  float* WWm   = ws + 15360000;   //  2,560,000  (overlays A)
  float* biasN = ws + 17920000;   //    320,000  (overlays A)
  float* xwc   = ws + 18240000;   //  1,280,000  (overlays A)
  float* rmax  = ws + 25000000;   //      5,120
  float* rsum  = ws + 25005120;   //      5,120
  float* Xr    = ws + 25010240;   //  2,560,000
  float* Y1    = ws + 27570240;   //  2,560,000
  float* Y2    = ws + 30130240;   //  2,560,000

  build_A_kernel<<<dim3(79, 79), dim3(16, 16), 0, stream>>>(emb, A);
  row_stats_kernel<<<NN, 256, 0, stream>>>(A, rmax, rsum);
  transpose_x_kernel<<<(NN * BC + 255) / 256, 256, 0, stream>>>(x, Xr);
  gemm_softmax_kernel<<<dim3(8, 79), 256, 0, stream>>>(A, rmax, rsum, Xr, Y1);
  gemm_softmax_kernel<<<dim3(8, 79), 256, 0, stream>>>(A, rmax, rsum, Y1, Y2);
  emb_gemm_kernel<<<dim3(48, 157), 256, 0, stream>>>(emb, wpool, Wm, NN, 3072);
  emb_gemm_kernel<<<dim3(8, 157), 256, 0, stream>>>(emb, wwin, WWm, NN, 512);
  emb_gemm_kernel<<<dim3(1, 157), 256, 0, stream>>>(emb, bpool, biasN, NN, 64);
  window_combine_kernel<<<(BB * NN * 16 + 255) / 256, 256, 0, stream>>>(xwin, T, xwc);
  fuse_out_kernel<<<NN, 256, 0, stream>>>(x, Y1, Y2, Wm, WWm, biasN, xwc,
                                          ln1w, ln1b, ln2w, ln2b, out);
}

// Round 2
// 721.018 us; speedup vs baseline: 1.8157x; 1.8157x over previous
//
#include <hip/hip_runtime.h>
#include <hip/hip_bf16.h>

// Problem constants (reference setup_inputs)
#define NN   5000   // nodes
#define EDIM 64     // embedding dim
#define DINC 32     // DIN
#define BB   16     // batch
#define LAGN 12     // LAG
#define BC   512    // BB*DINC

typedef __attribute__((ext_vector_type(8))) short short8;   // 8 bf16 = 4 VGPRs
typedef __attribute__((ext_vector_type(4))) float float4v;  // MFMA 16x16 C/D

static __device__ __forceinline__ ushort f2bf(float x) {
  __hip_bfloat16 h = __float2bfloat16(x);
  return *reinterpret_cast<ushort*>(&h);
}

// ---------------------------------------------------------------------------
// K1: A = relu(emb @ emb^T), [NN, NN] fp32, row-major stride NN. (unchanged)
// ---------------------------------------------------------------------------
__global__ __launch_bounds__(256) void build_A_kernel(const float* __restrict__ emb,
                                                      float* __restrict__ A) {
  __shared__ float Er[64][EDIM + 1];
  __shared__ float Ec[64][EDIM + 1];
  const int row0 = blockIdx.y * 64, col0 = blockIdx.x * 64;
  const int tid = threadIdx.y * 16 + threadIdx.x;
  for (int i = tid; i < 1024; i += 256) {
    const int r = i >> 4, d4 = (i & 15) << 2;
    const int gr = row0 + r, gc = col0 + r;
    float4 v = make_float4(0.f, 0.f, 0.f, 0.f);
    float4 w = make_float4(0.f, 0.f, 0.f, 0.f);
    if (gr < NN) v = *(const float4*)(emb + gr * EDIM + d4);
    if (gc < NN) w = *(const float4*)(emb + gc * EDIM + d4);
    Er[r][d4 + 0] = v.x; Er[r][d4 + 1] = v.y; Er[r][d4 + 2] = v.z; Er[r][d4 + 3] = v.w;
    Ec[r][d4 + 0] = w.x; Ec[r][d4 + 1] = w.y; Ec[r][d4 + 2] = w.z; Ec[r][d4 + 3] = w.w;
  }
  __syncthreads();
  const int ty = threadIdx.y, tx = threadIdx.x;
  float acc[4][4] = {};
  for (int d = 0; d < EDIM; ++d) {
    float a[4], b[4];
#pragma unroll
    for (int r = 0; r < 4; ++r) a[r] = Er[ty + r * 16][d];
#pragma unroll
    for (int c = 0; c < 4; ++c) b[c] = Ec[tx + c * 16][d];
#pragma unroll
    for (int r = 0; r < 4; ++r)
#pragma unroll
      for (int c = 0; c < 4; ++c) acc[r][c] = fmaf(a[r], b[c], acc[r][c]);
  }
#pragma unroll
  for (int r = 0; r < 4; ++r) {
    const int gr = row0 + ty + r * 16;
    if (gr >= NN) continue;
#pragma unroll
    for (int c = 0; c < 4; ++c) {
      const int gc = col0 + tx + c * 16;
      if (gc < NN) A[(size_t)gr * NN + gc] = fmaxf(acc[r][c], 0.f);
    }
  }
}

// ---------------------------------------------------------------------------
// K2: fused row-softmax -> bf16, IN PLACE over A. One block per row; the row
// is staged in LDS so A is read exactly once. P[m][k] lives at
// ((ushort*)A)[m*10000 + k]  (row stride 10000 ushorts, first 5000 used).
// ---------------------------------------------------------------------------
__global__ __launch_bounds__(256) void convert_P_kernel(float* __restrict__ A) {
  const int m = blockIdx.x;
  float* row = A + (size_t)m * NN;
  __shared__ float buf[NN];
  __shared__ float red[256];
  const int tid = threadIdx.x;
  float mx = 0.f;  // relu >= 0, diag > 0
  for (int i = tid; i < 1250; i += 256) {
    float4 v = *(const float4*)(row + i * 4);
    *(float4*)(buf + i * 4) = v;
    mx = fmaxf(mx, fmaxf(fmaxf(v.x, v.y), fmaxf(v.z, v.w)));
  }
  red[tid] = mx; __syncthreads();
  for (int s = 128; s > 0; s >>= 1) {
    if (tid < s) red[tid] = fmaxf(red[tid], red[tid + s]);
    __syncthreads();
  }
  mx = red[0]; __syncthreads();
  float sum = 0.f;
  for (int i = tid; i < 1250; i += 256) {
    float4 v = *(const float4*)(buf + i * 4);
    v.x = __expf(v.x - mx); v.y = __expf(v.y - mx);
    v.z = __expf(v.z - mx); v.w = __expf(v.w - mx);
    *(float4*)(buf + i * 4) = v;
    sum += v.x + v.y + v.z + v.w;
  }
  red[tid] = sum; __syncthreads();
  for (int s = 128; s > 0; s >>= 1) {
    if (tid < s) red[tid] += red[tid + s];
    __syncthreads();
  }
  const float inv = 1.f / red[0];
  ushort* prow = (ushort*)row;  // in-place: bytes 0..9999 of this row
  for (int i = tid; i < 1250; i += 256) {
    float4 v = *(const float4*)(buf + i * 4);
    ushort4 o;
    o.x = f2bf(v.x * inv); o.y = f2bf(v.y * inv);
    o.z = f2bf(v.z * inv); o.w = f2bf(v.w * inv);
    *(ushort4*)(prow + i * 4) = o;
  }
}

// ---------------------------------------------------------------------------
// K3: XbT[b*32+c][m] = bf16(x[b][m][c])   ([512][5000] bf16, B^T layout)
// ---------------------------------------------------------------------------
__global__ __launch_bounds__(256) void transpose_xb_kernel(const float* __restrict__ x,
                                                           ushort* __restrict__ XbT) {
  const int m = blockIdx.x * 256 + threadIdx.x;
  const int j = blockIdx.y;            // 0..511
  if (m >= NN) return;
  const int b = j >> 5, c = j & 31;
  XbT[(size_t)j * NN + m] = f2bf(x[((size_t)b * NN + m) * DINC + c]);
}

// ---------------------------------------------------------------------------
// K4/K5: bf16 MFMA GEMM  C[m][n] = sum_k P[m][k] * Bt[n][k]
//   P: [NN][ldp=10000 ushort] bf16 (in-place over A);  Bt: [512][NN] bf16.
//   Cf fp32 [NN][512]; optional Ct bf16 [512][NN] (= C^T, for GEMM2's Bt).
// BM=32, BN=128, BK=32; 128 threads = 2 waves (wave w covers cols w*64..+63,
// 2x4 grid of 16x16x32 MFMAs). LDS tiles in XOR-swizzled 16B granules:
// granule (row r, chunk c) stored at (r*4 + (c ^ (r&3)))*16B -> conflict-free
// b128 reads/writes, 16B aligned.
// ---------------------------------------------------------------------------
__global__ __launch_bounds__(128) void mfma_gemm_kernel(const ushort* __restrict__ Pm,
                                                        const ushort* __restrict__ Bt,
                                                        float* __restrict__ Cf,
                                                        ushort* __restrict__ Ct,
                                                        int writeT) {
  __shared__ __align__(16) ushort smem[5120];  // As: [0,1024) | Bs: [1024,5120)
  ushort* As = smem;
  ushort* Bs = smem + 1024;
  const int tid = threadIdx.x;
  const int w = tid >> 6, l = tid & 63;
  const int fm = l & 15;      // frag row within 16-tile
  const int kq = l >> 4;      // k-quad 0..3 (k = kq*8 + j)
  const int row0 = blockIdx.y * 32, col0 = blockIdx.x * 128;
  // A staging: one 16B granule per thread: row am, chunk ac
  const int am = tid >> 2, ac = tid & 3;
  const bool arow_ok = (row0 + am) < NN;
  const ushort* agp = Pm + (size_t)(row0 + am) * 10000 + ac * 8;
  const int a_lds = (am * 4 + (ac ^ (am & 3))) * 8;
  // frag LDS offsets (constant across K since chunk == kq)
  int aoff[2], boff[4];
#pragma unroll
  for (int mt = 0; mt < 2; ++mt) {
    const int r = mt * 16 + fm;
    aoff[mt] = (r * 4 + (kq ^ (r & 3))) * 8;
  }
#pragma unroll
  for (int nt = 0; nt < 4; ++nt) {
    const int r = w * 64 + nt * 16 + fm;
    boff[nt] = (r * 4 + (kq ^ (r & 3))) * 8;
  }
  float4v acc[2][4] = {};
  for (int kt = 0; kt < 157; ++kt) {
    const int k0 = kt * 32;
    __syncthreads();
    {  // stage A (32x32 bf16)
      uint4 av = make_uint4(0, 0, 0, 0);
      if (arow_ok && (k0 + ac * 8) < NN) av = *(const uint4*)(agp + k0);
      *(uint4*)(As + a_lds) = av;
    }
#pragma unroll
    for (int i = 0; i < 4; ++i) {  // stage Bt (128x32 bf16)
      const int ci = tid + i * 128;
      const int bn = ci >> 2, bc = ci & 3;
      uint4 bv = make_uint4(0, 0, 0, 0);
      if ((k0 + bc * 8) < NN)
        bv = *(const uint4*)(Bt + (size_t)(col0 + bn) * NN + k0 + bc * 8);
      *(uint4*)(Bs + (bn * 4 + (bc ^ (bn & 3))) * 8) = bv;
    }
    __syncthreads();
    const short8 a0 = *(const short8*)(As + aoff[0]);
    const short8 a1 = *(const short8*)(As + aoff[1]);
#pragma unroll
    for (int nt = 0; nt < 4; ++nt) {
      const short8 b = *(const short8*)(Bs + boff[nt]);
      acc[0][nt] = __builtin_amdgcn_mfma_f32_16x16x32_bf16(a0, b, acc[0][nt], 0, 0, 0);
      acc[1][nt] = __builtin_amdgcn_mfma_f32_16x16x32_bf16(a1, b, acc[1][nt], 0, 0, 0);
    }
  }
  // epilogue: Cf (fp32, coalesced 16-lane col groups)
  const int cbase = col0 + w * 64 + fm;
#pragma unroll
  for (int mt = 0; mt < 2; ++mt)
#pragma unroll
    for (int r = 0; r < 4; ++r) {
      const int gm = row0 + mt * 16 + kq * 4 + r;
      if (gm < NN) {
        float* crow = Cf + (size_t)gm * BC + cbase;
#pragma unroll
        for (int nt = 0; nt < 4; ++nt) crow[nt * 16] = acc[mt][nt][r];
      }
    }
  if (writeT) {  // C^T bf16 via LDS bounce (reuses smem: [128][40] ushorts)
    __syncthreads();
    ushort* Tt = smem;
#pragma unroll
    for (int nt = 0; nt < 4; ++nt) {
      const int nloc = w * 64 + nt * 16 + fm;
#pragma unroll
      for (int mt = 0; mt < 2; ++mt)
#pragma unroll
        for (int r = 0; r < 4; ++r)
          Tt[nloc * 40 + mt * 16 + kq * 4 + r] = f2bf(acc[mt][nt][r]);
    }
    __syncthreads();
#pragma unroll
    for (int i = 0; i < 4; ++i) {
      const int ci = tid + i * 128;
      const int n = ci >> 2, mc = ci & 3;
      if (row0 + mc * 8 < NN)
        *(uint4*)(Ct + (size_t)(col0 + n) * NN + row0 + mc * 8) =
            *(const uint4*)(Tt + n * 40 + mc * 8);
    }
  }
}

// ---------------------------------------------------------------------------
// K6/K7/K8: C[M, Nc] = emb[M, 64] @ Bw[64, Nc]  (unchanged)
// ---------------------------------------------------------------------------
__global__ __launch_bounds__(256) void emb_gemm_kernel(const float* __restrict__ Ae,
                                                       const float* __restrict__ Bw,
                                                       float* __restrict__ C,
                                                       int M, int Nc) {
  __shared__ float Aet[EDIM][32];
  __shared__ __align__(16) float Bs[EDIM][64];
  const int row0 = blockIdx.y * 32, col0 = blockIdx.x * 64;
  const int tid = threadIdx.x;
  for (int i = tid; i < 512; i += 256) {
    const int r = i >> 4, d4 = (i & 15) << 2;
    const int gm = row0 + r;
    float4 v = make_float4(0.f, 0.f, 0.f, 0.f);
    if (gm < M) v = *(const float4*)(Ae + (size_t)gm * EDIM + d4);
    Aet[d4 + 0][r] = v.x; Aet[d4 + 1][r] = v.y; Aet[d4 + 2][r] = v.z; Aet[d4 + 3][r] = v.w;
  }
  for (int i = tid; i < 1024; i += 256) {
    const int br = i >> 4, bc = (i & 15) << 2;
    *(float4*)&Bs[br][bc] = *(const float4*)(Bw + (size_t)br * Nc + col0 + bc);
  }
  __syncthreads();
  const int ty = tid >> 4, tx = tid & 15;
  float acc[2][4] = {};
#pragma unroll 8
  for (int d = 0; d < EDIM; ++d) {
    const float a0 = Aet[d][ty * 2], a1 = Aet[d][ty * 2 + 1];
    const float4 b4 = *(const float4*)&Bs[d][tx << 2];
    acc[0][0] = fmaf(a0, b4.x, acc[0][0]); acc[0][1] = fmaf(a0, b4.y, acc[0][1]);
    acc[0][2] = fmaf(a0, b4.z, acc[0][2]); acc[0][3] = fmaf(a0, b4.w, acc[0][3]);
    acc[1][0] = fmaf(a1, b4.x, acc[1][0]); acc[1][1] = fmaf(a1, b4.y, acc[1][1]);
    acc[1][2] = fmaf(a1, b4.z, acc[1][2]); acc[1][3] = fmaf(a1, b4.w, acc[1][3]);
  }
#pragma unroll
  for (int r = 0; r < 2; ++r) {
    const int gm = row0 + ty * 2 + r;
    if (gm >= M) continue;
    float4 o;
    o.x = acc[r][0]; o.y = acc[r][1]; o.z = acc[r][2]; o.w = acc[r][3];
    *(float4*)(C + (size_t)gm * Nc + col0 + (tx << 2)) = o;
  }
}

// ---------------------------------------------------------------------------
// K9: xwc[b, n, i] = sum_t T[t] * x_window[b, t, n, i]  (unchanged)
// ---------------------------------------------------------------------------
__global__ __launch_bounds__(256) void window_combine_kernel(const float* __restrict__ xw,
                                                             const float* __restrict__ T,
                                                             float* __restrict__ out) {
  const int idx = blockIdx.x * 256 + threadIdx.x;
  if (idx >= BB * NN * 16) return;
  const int b = idx / (NN * 16);
  const int rem = idx - b * (NN * 16);
  float acc = 0.f;
#pragma unroll
  for (int t = 0; t < LAGN; ++t)
    acc = fmaf(T[t], xw[(size_t)(b * LAGN + t) * (NN * 16) + rem], acc);
  out[idx] = acc;
}

// ---------------------------------------------------------------------------
// K10: per-node fusion (unchanged)
// ---------------------------------------------------------------------------
__global__ __launch_bounds__(256) void fuse_out_kernel(const float* __restrict__ x,
                                                       const float* __restrict__ Y1,
                                                       const float* __restrict__ Y2,
                                                       const float* __restrict__ W,
                                                       const float* __restrict__ WWm,
                                                       const float* __restrict__ biasN,
                                                       const float* __restrict__ xwc,
                                                       const float* __restrict__ ln1w,
                                                       const float* __restrict__ ln1b,
                                                       const float* __restrict__ ln2w,
                                                       const float* __restrict__ ln2b,
                                                       float* __restrict__ out) {
  const int n = blockIdx.x;
  __shared__ __align__(16) float Wn[3072];
  __shared__ __align__(16) float WWn[512];
  __shared__ __align__(16) float x0v[512], y1v[512], y2v[512];
  __shared__ __align__(16) float xwv[256];
  __shared__ __align__(16) float bv[64];
  const int tid = threadIdx.x;
  for (int i = tid; i < 768; i += 256)
    *(float4*)&Wn[i << 2] = *(const float4*)(W + (size_t)n * 3072 + (i << 2));
  if (tid < 128) {
    *(float4*)&WWn[tid << 2] = *(const float4*)(WWm + (size_t)n * 512 + (tid << 2));
    *(float4*)&y1v[tid << 2] = *(const float4*)(Y1 + (size_t)n * 512 + (tid << 2));
    *(float4*)&y2v[tid << 2] = *(const float4*)(Y2 + (size_t)n * 512 + (tid << 2));
    const int b = tid >> 3, c4 = (tid & 7) << 2;
    *(float4*)&x0v[(b << 5) + c4] = *(const float4*)(x + ((size_t)b * NN + n) * DINC + c4);
  }
  if (tid < 64) {
    const int b = tid >> 2, i4 = (tid & 3) << 2;
    *(float4*)&xwv[(b << 4) + i4] = *(const float4*)(xwc + ((size_t)b * NN + n) * 16 + i4);
  }
  if (tid < 16)
    *(float4*)&bv[tid << 2] = *(const float4*)(biasN + (size_t)n * 64 + (tid << 2));
  __syncthreads();
  const int o = tid & 31, bg = tid >> 5;
  const float w1 = ln1w[o], b1 = ln1b[o], w2 = ln2w[o], b2 = ln2b[o];
  const float bvg = bv[o], bvw = bv[32 + o];
#pragma unroll
  for (int rep = 0; rep < 2; ++rep) {
    const int b = bg + (rep << 3);
    float gv = 0.f;
#pragma unroll
    for (int i = 0; i < 32; ++i) gv = fmaf(x0v[(b << 5) + i], Wn[i * 32 + o], gv);
#pragma unroll
    for (int i = 0; i < 32; ++i) gv = fmaf(y1v[(b << 5) + i], Wn[1024 + i * 32 + o], gv);
#pragma unroll
    for (int i = 0; i < 32; ++i) gv = fmaf(y2v[(b << 5) + i], Wn[2048 + i * 32 + o], gv);
    float wv = 0.f;
#pragma unroll
    for (int i = 0; i < 16; ++i) wv = fmaf(xwv[(b << 4) + i], WWn[i * 32 + o], wv);
    float s1 = gv, s2 = gv * gv;
#pragma unroll
    for (int m = 16; m >= 1; m >>= 1) { s1 += __shfl_xor(s1, m, 32); s2 += __shfl_xor(s2, m, 32); }
    const float mu = s1 * 0.03125f;
    const float var = s2 * 0.03125f - mu * mu;
    const float og = (gv - mu) * rsqrtf(var + 1e-5f) * w1 + b1 + bvg;
    float t1 = wv, t2 = wv * wv;
#pragma unroll
    for (int m = 16; m >= 1; m >>= 1) { t1 += __shfl_xor(t1, m, 32); t2 += __shfl_xor(t2, m, 32); }
    const float mu2 = t1 * 0.03125f;
    const float var2 = t2 * 0.03125f - mu2 * mu2;
    const float ow = (wv - mu2) * rsqrtf(var2 + 1e-5f) * w2 + b2 + bvw;
    float* op = out + ((size_t)b * NN + n) * 64;
    op[o] = og;
    op[32 + o] = ow;
  }
}

// ---------------------------------------------------------------------------
// Workspace (fp32 slots), total 32,680,000 = 130.7 MB:
//   [0, 25M)      : A fp32 -> P bf16 in place (GEMM operand, dead after GEMM2)
//                   then OVERLAID by Wm/WWm/biasN/xwc (emb_gemms run after GEMM2)
//   [25.00M,26.28M): XbT bf16   [26.28M,27.56M): Y1t bf16
//   [27.56M,30.12M): Y1f fp32   [30.12M,32.68M): Y2f fp32
// ---------------------------------------------------------------------------
extern "C" void kernel_launch(void* const* d_in, const int* in_sizes, int n_in,
                              void* d_out, int out_size, void* d_ws, size_t ws_size,
                              hipStream_t stream) {
  const float* x     = (const float*)d_in[0];
  const float* xwin  = (const float*)d_in[1];
  const float* emb   = (const float*)d_in[2];
  const float* wpool = (const float*)d_in[3];
  const float* wwin  = (const float*)d_in[4];
  const float* bpool = (const float*)d_in[5];
  const float* T     = (const float*)d_in[6];
  const float* ln1w  = (const float*)d_in[7];
  const float* ln1b  = (const float*)d_in[8];
  const float* ln2w  = (const float*)d_in[9];
  const float* ln2b  = (const float*)d_in[10];
  float* out = (float*)d_out;
  float* ws = (float*)d_ws;

  float*  A   = ws;
  ushort* P   = (ushort*)ws;                      // ldp = 10000 ushorts
  ushort* XbT = (ushort*)(ws + 25000000);
  ushort* Y1t = (ushort*)(ws + 26280000);
  float*  Y1f = ws + 27560000;
  float*  Y2f = ws + 30120000;
  float*  Wm    = ws;                             // overlays P after GEMM2
  float*  WWm   = ws + 15360000;
  float*  biasN = ws + 17920000;
  float*  xwc   = ws + 18240000;

  build_A_kernel<<<dim3(79, 79), dim3(16, 16), 0, stream>>>(emb, A);
  convert_P_kernel<<<NN, 256, 0, stream>>>(A);
  transpose_xb_kernel<<<dim3(20, 512), 256, 0, stream>>>(x, XbT);
  mfma_gemm_kernel<<<dim3(4, 157), 128, 0, stream>>>(P, XbT, Y1f, Y1t, 1);
  mfma_gemm_kernel<<<dim3(4, 157), 128, 0, stream>>>(P, Y1t, Y2f, (ushort*)nullptr, 0);
  emb_gemm_kernel<<<dim3(48, 157), 256, 0, stream>>>(emb, wpool, Wm, NN, 3072);
  emb_gemm_kernel<<<dim3(8, 157), 256, 0, stream>>>(emb, wwin, WWm, NN, 512);
  emb_gemm_kernel<<<dim3(1, 157), 256, 0, stream>>>(emb, bpool, biasN, NN, 64);
  window_combine_kernel<<<(BB * NN * 16 + 255) / 256, 256, 0, stream>>>(xwin, T, xwc);
  fuse_out_kernel<<<NN, 256, 0, stream>>>(x, Y1f, Y2f, Wm, WWm, biasN, xwc,
                                          ln1w, ln1b, ln2w, ln2b, out);
}

// Round 3
// 503.072 us; speedup vs baseline: 2.6024x; 1.4332x over previous
//
#include <hip/hip_runtime.h>
#include <hip/hip_bf16.h>

// Problem constants (reference setup_inputs)
#define NN   5000   // nodes
#define EDIM 64     // embedding dim
#define DINC 32     // DIN
#define BB   16     // batch
#define LAGN 12     // LAG
#define BC   512    // BB*DINC
#define KPAD 5120   // k-extent padded to 128-tile multiple (zeros in [5000,5120))

typedef __attribute__((ext_vector_type(8))) short short8;   // 8 bf16 = 4 VGPRs
typedef __attribute__((ext_vector_type(4))) float float4v;  // MFMA 16x16 C/D

static __device__ __forceinline__ ushort f2bf(float x) {
  __hip_bfloat16 h = __float2bfloat16(x);
  return *reinterpret_cast<ushort*>(&h);
}

// async global->LDS DMA, 16 B per lane; LDS layout = lane order (wave-uniform
// base + lane*16). All calls are unconditional (no exec masking).
static __device__ __forceinline__ void gll16(const ushort* g, ushort* l) {
  __builtin_amdgcn_global_load_lds(
      (const __attribute__((address_space(1))) void*)g,
      (__attribute__((address_space(3))) void*)l, 16, 0, 0);
}

// ---------------------------------------------------------------------------
// K1: A = relu(emb @ emb^T), [NN, NN] fp32, row-major stride NN.
// ---------------------------------------------------------------------------
__global__ __launch_bounds__(256) void build_A_kernel(const float* __restrict__ emb,
                                                      float* __restrict__ A) {
  __shared__ float Er[64][EDIM + 1];
  __shared__ float Ec[64][EDIM + 1];
  const int row0 = blockIdx.y * 64, col0 = blockIdx.x * 64;
  const int tid = threadIdx.y * 16 + threadIdx.x;
  for (int i = tid; i < 1024; i += 256) {
    const int r = i >> 4, d4 = (i & 15) << 2;
    const int gr = row0 + r, gc = col0 + r;
    float4 v = make_float4(0.f, 0.f, 0.f, 0.f);
    float4 w = make_float4(0.f, 0.f, 0.f, 0.f);
    if (gr < NN) v = *(const float4*)(emb + gr * EDIM + d4);
    if (gc < NN) w = *(const float4*)(emb + gc * EDIM + d4);
    Er[r][d4 + 0] = v.x; Er[r][d4 + 1] = v.y; Er[r][d4 + 2] = v.z; Er[r][d4 + 3] = v.w;
    Ec[r][d4 + 0] = w.x; Ec[r][d4 + 1] = w.y; Ec[r][d4 + 2] = w.z; Ec[r][d4 + 3] = w.w;
  }
  __syncthreads();
  const int ty = threadIdx.y, tx = threadIdx.x;
  float acc[4][4] = {};
  for (int d = 0; d < EDIM; ++d) {
    float a[4], b[4];
#pragma unroll
    for (int r = 0; r < 4; ++r) a[r] = Er[ty + r * 16][d];
#pragma unroll
    for (int c = 0; c < 4; ++c) b[c] = Ec[tx + c * 16][d];
#pragma unroll
    for (int r = 0; r < 4; ++r)
#pragma unroll
      for (int c = 0; c < 4; ++c) acc[r][c] = fmaf(a[r], b[c], acc[r][c]);
  }
#pragma unroll
  for (int r = 0; r < 4; ++r) {
    const int gr = row0 + ty + r * 16;
    if (gr >= NN) continue;
#pragma unroll
    for (int c = 0; c < 4; ++c) {
      const int gc = col0 + tx + c * 16;
      if (gc < NN) A[(size_t)gr * NN + gc] = fmaxf(acc[r][c], 0.f);
    }
  }
}

// ---------------------------------------------------------------------------
// K2: fused row-softmax -> bf16, IN PLACE over A. P[m][k] at
// ((ushort*)A)[m*10000 + k], k < 5120 valid (k in [5000,5120) zeroed for the
// padded MFMA K-loop). Floats [m*5000+2564, +2048) of each row stay free for
// split-K partials.
// ---------------------------------------------------------------------------
__global__ __launch_bounds__(256) void convert_P_kernel(float* __restrict__ A) {
  const int m = blockIdx.x;
  float* row = A + (size_t)m * NN;
  __shared__ float buf[NN];
  __shared__ float red[256];
  const int tid = threadIdx.x;
  float mx = 0.f;  // relu >= 0, diag > 0
  for (int i = tid; i < 1250; i += 256) {
    float4 v = *(const float4*)(row + i * 4);
    *(float4*)(buf + i * 4) = v;
    mx = fmaxf(mx, fmaxf(fmaxf(v.x, v.y), fmaxf(v.z, v.w)));
  }
  red[tid] = mx; __syncthreads();
  for (int s = 128; s > 0; s >>= 1) {
    if (tid < s) red[tid] = fmaxf(red[tid], red[tid + s]);
    __syncthreads();
  }
  mx = red[0]; __syncthreads();
  float sum = 0.f;
  for (int i = tid; i < 1250; i += 256) {
    float4 v = *(const float4*)(buf + i * 4);
    v.x = __expf(v.x - mx); v.y = __expf(v.y - mx);
    v.z = __expf(v.z - mx); v.w = __expf(v.w - mx);
    *(float4*)(buf + i * 4) = v;
    sum += v.x + v.y + v.z + v.w;
  }
  red[tid] = sum; __syncthreads();
  for (int s = 128; s > 0; s >>= 1) {
    if (tid < s) red[tid] += red[tid + s];
    __syncthreads();
  }
  const float inv = 1.f / red[0];
  ushort* prow = (ushort*)row;
  for (int i = tid; i < 1250; i += 256) {
    float4 v = *(const float4*)(buf + i * 4);
    ushort4 o;
    o.x = f2bf(v.x * inv); o.y = f2bf(v.y * inv);
    o.z = f2bf(v.z * inv); o.w = f2bf(v.w * inv);
    *(ushort4*)(prow + i * 4) = o;
  }
  if (tid < 120) prow[5000 + tid] = 0;  // k-pad zeros for the MFMA loop
}

// ---------------------------------------------------------------------------
// K3: XbT[b*32+c][m] = bf16(x[b][m][c]); [512][KPAD] bf16, zero pad m>=5000.
// ---------------------------------------------------------------------------
__global__ __launch_bounds__(256) void transpose_xb_kernel(const float* __restrict__ x,
                                                           ushort* __restrict__ XbT) {
  const int m = blockIdx.x * 256 + threadIdx.x;  // 0..5119 (grid 20*256)
  const int j = blockIdx.y;                      // 0..511
  const int b = j >> 5, c = j & 31;
  ushort v = 0;
  if (m < NN) v = f2bf(x[((size_t)b * NN + m) * DINC + c]);
  XbT[(size_t)j * KPAD + m] = v;
}

// ---------------------------------------------------------------------------
// K4/K6: bf16 MFMA GEMM, m97 structure. C_partial[m][n] = sum_k P[m][k]*Bt[n][k]
//   P: [.][ldp=10000] bf16 (k<5120 valid); Bt: [512][5120] bf16 (zero-padded).
//   BM=BN=128, BK=32, 256 thr = 4 waves (2x2), wave tile 64x64 (4x4 MFMAs).
//   Split-K=4 via blockIdx.z (k-chunk 1280 = 40 iters); fp32 partials written
//   into the free half of each P row: ws[m*5000 + 2564 + z*512 + n].
//   Staging via global_load_lds width=16; LDS row-major [row][32k].
//   All loads unconditional: row overrun (<5120) reads in-bounds garbage that
//   only lands in discarded (gm>=5000) accumulator rows; k overrun hits pad
//   zeros. Epilogue guards gm<5000.
// ---------------------------------------------------------------------------
__global__ __launch_bounds__(256) void mfma_gemm_kernel(const ushort* __restrict__ Pm,
                                                        const ushort* __restrict__ Bt,
                                                        float* __restrict__ wsb) {
  __shared__ __align__(16) ushort As[4096];  // [128][32]
  __shared__ __align__(16) ushort Bs[4096];  // [128][32]
  const int tid = threadIdx.x;
  const int w = tid >> 6, l = tid & 63;
  const int fm = l & 15, kq = l >> 4;
  const int wm = w >> 1, wn = w & 1;
  const int row0 = blockIdx.y * 128, col0 = blockIdx.x * 128;
  const int kbase = blockIdx.z * 1280;
  // staging granule: g = tid (+256): row = g>>2, k-chunk = (g&3)*8
  const int ra = tid >> 2, ca = (tid & 3) << 3;
  const ushort* gA0 = Pm + (size_t)(row0 + ra) * 10000 + kbase + ca;
  const ushort* gA1 = gA0 + (size_t)64 * 10000;
  const ushort* gB0 = Bt + (size_t)(col0 + ra) * KPAD + kbase + ca;
  const ushort* gB1 = gB0 + (size_t)64 * KPAD;
  ushort* lA0 = As + tid * 8;  ushort* lA1 = As + (tid + 256) * 8;
  ushort* lB0 = Bs + tid * 8;  ushort* lB1 = Bs + (tid + 256) * 8;
  int aoff[4], boff[4];
#pragma unroll
  for (int mt = 0; mt < 4; ++mt) aoff[mt] = (wm * 64 + mt * 16 + fm) * 32 + kq * 8;
#pragma unroll
  for (int nt = 0; nt < 4; ++nt) boff[nt] = (wn * 64 + nt * 16 + fm) * 32 + kq * 8;
  float4v acc[4][4] = {};
  for (int kt = 0; kt < 40; ++kt) {
    const int k0 = kt * 32;
    __syncthreads();  // prior-iter frag reads done before DMA overwrites LDS
    gll16(gA0 + k0, lA0);
    gll16(gA1 + k0, lA1);
    gll16(gB0 + k0, lB0);
    gll16(gB1 + k0, lB1);
    __syncthreads();  // compiler drains vmcnt(0) before s_barrier -> LDS ready
    short8 a[4], b[4];
#pragma unroll
    for (int mt = 0; mt < 4; ++mt) a[mt] = *(const short8*)(As + aoff[mt]);
#pragma unroll
    for (int nt = 0; nt < 4; ++nt) b[nt] = *(const short8*)(Bs + boff[nt]);
#pragma unroll
    for (int mt = 0; mt < 4; ++mt)
#pragma unroll
      for (int nt = 0; nt < 4; ++nt)
        acc[mt][nt] = __builtin_amdgcn_mfma_f32_16x16x32_bf16(a[mt], b[nt], acc[mt][nt], 0, 0, 0);
  }
  // epilogue -> strided partial slab in the P rows' free halves
  const int cb = col0 + wn * 64 + fm;
  float* Cp = wsb + 2564 + blockIdx.z * 512;
#pragma unroll
  for (int mt = 0; mt < 4; ++mt)
#pragma unroll
    for (int r = 0; r < 4; ++r) {
      const int gm = row0 + wm * 64 + mt * 16 + kq * 4 + r;
      if (gm < NN) {
        float* crow = Cp + (size_t)gm * 5000 + cb;
#pragma unroll
        for (int nt = 0; nt < 4; ++nt) crow[nt * 16] = acc[mt][nt][r];
      }
    }
}

// ---------------------------------------------------------------------------
// K5/K7: sum 4 split-K partials -> Yf fp32 [5000][512]; optionally also write
// Yt bf16 [512][KPAD] (transposed, zero-padded m in [5000,5120)).
// Tile 64m x 64n, grid (8, 80).
// ---------------------------------------------------------------------------
__global__ __launch_bounds__(256) void reduce_kernel(const float* __restrict__ wsb,
                                                     float* __restrict__ Yf,
                                                     ushort* __restrict__ Yt,
                                                     int writeT) {
  const int m0 = blockIdx.y * 64, n0 = blockIdx.x * 64;
  __shared__ __align__(16) ushort Lt[64][80];  // [n][m], 16B-aligned rows
  const int tid = threadIdx.x;
  const int mi = tid >> 4, nl4 = (tid & 15) << 2;
#pragma unroll
  for (int s = 0; s < 4; ++s) {
    const int m = m0 + mi + s * 16;
    float4 sum = make_float4(0.f, 0.f, 0.f, 0.f);
    if (m < NN) {
      const float* pr = wsb + (size_t)m * 5000 + 2564 + n0 + nl4;
#pragma unroll
      for (int p = 0; p < 4; ++p) {
        float4 v = *(const float4*)(pr + p * 512);
        sum.x += v.x; sum.y += v.y; sum.z += v.z; sum.w += v.w;
      }
      *(float4*)(Yf + (size_t)m * BC + n0 + nl4) = sum;
    }
    if (writeT) {
      const int ml = mi + s * 16;
      Lt[nl4 + 0][ml] = f2bf(sum.x);
      Lt[nl4 + 1][ml] = f2bf(sum.y);
      Lt[nl4 + 2][ml] = f2bf(sum.z);
      Lt[nl4 + 3][ml] = f2bf(sum.w);
    }
  }
  if (writeT) {
    __syncthreads();
#pragma unroll
    for (int i = 0; i < 2; ++i) {
      const int g = tid + i * 256;
      const int nl = g >> 3, gi = g & 7;
      *(uint4*)(Yt + (size_t)(n0 + nl) * KPAD + m0 + gi * 8) =
          *(const uint4*)(&Lt[nl][gi * 8]);
    }
  }
}

// ---------------------------------------------------------------------------
// K8/K9/K10: C[M, Nc] = emb[M, 64] @ Bw[64, Nc]
// ---------------------------------------------------------------------------
__global__ __launch_bounds__(256) void emb_gemm_kernel(const float* __restrict__ Ae,
                                                       const float* __restrict__ Bw,
                                                       float* __restrict__ C,
                                                       int M, int Nc) {
  __shared__ float Aet[EDIM][32];
  __shared__ __align__(16) float Bs[EDIM][64];
  const int row0 = blockIdx.y * 32, col0 = blockIdx.x * 64;
  const int tid = threadIdx.x;
  for (int i = tid; i < 512; i += 256) {
    const int r = i >> 4, d4 = (i & 15) << 2;
    const int gm = row0 + r;
    float4 v = make_float4(0.f, 0.f, 0.f, 0.f);
    if (gm < M) v = *(const float4*)(Ae + (size_t)gm * EDIM + d4);
    Aet[d4 + 0][r] = v.x; Aet[d4 + 1][r] = v.y; Aet[d4 + 2][r] = v.z; Aet[d4 + 3][r] = v.w;
  }
  for (int i = tid; i < 1024; i += 256) {
    const int br = i >> 4, bc = (i & 15) << 2;
    *(float4*)&Bs[br][bc] = *(const float4*)(Bw + (size_t)br * Nc + col0 + bc);
  }
  __syncthreads();
  const int ty = tid >> 4, tx = tid & 15;
  float acc[2][4] = {};
#pragma unroll 8
  for (int d = 0; d < EDIM; ++d) {
    const float a0 = Aet[d][ty * 2], a1 = Aet[d][ty * 2 + 1];
    const float4 b4 = *(const float4*)&Bs[d][tx << 2];
    acc[0][0] = fmaf(a0, b4.x, acc[0][0]); acc[0][1] = fmaf(a0, b4.y, acc[0][1]);
    acc[0][2] = fmaf(a0, b4.z, acc[0][2]); acc[0][3] = fmaf(a0, b4.w, acc[0][3]);
    acc[1][0] = fmaf(a1, b4.x, acc[1][0]); acc[1][1] = fmaf(a1, b4.y, acc[1][1]);
    acc[1][2] = fmaf(a1, b4.z, acc[1][2]); acc[1][3] = fmaf(a1, b4.w, acc[1][3]);
  }
#pragma unroll
  for (int r = 0; r < 2; ++r) {
    const int gm = row0 + ty * 2 + r;
    if (gm >= M) continue;
    float4 o;
    o.x = acc[r][0]; o.y = acc[r][1]; o.z = acc[r][2]; o.w = acc[r][3];
    *(float4*)(C + (size_t)gm * Nc + col0 + (tx << 2)) = o;
  }
}

// ---------------------------------------------------------------------------
// K11: xwc[b, n, i] = sum_t T[t] * x_window[b, t, n, i]
// ---------------------------------------------------------------------------
__global__ __launch_bounds__(256) void window_combine_kernel(const float* __restrict__ xw,
                                                             const float* __restrict__ T,
                                                             float* __restrict__ out) {
  const int idx = blockIdx.x * 256 + threadIdx.x;
  if (idx >= BB * NN * 16) return;
  const int b = idx / (NN * 16);
  const int rem = idx - b * (NN * 16);
  float acc = 0.f;
#pragma unroll
  for (int t = 0; t < LAGN; ++t)
    acc = fmaf(T[t], xw[(size_t)(b * LAGN + t) * (NN * 16) + rem], acc);
  out[idx] = acc;
}

// ---------------------------------------------------------------------------
// K12: per-node fusion: gconv + wconv + LayerNorms + concat + bias
// ---------------------------------------------------------------------------
__global__ __launch_bounds__(256) void fuse_out_kernel(const float* __restrict__ x,
                                                       const float* __restrict__ Y1,
                                                       const float* __restrict__ Y2,
                                                       const float* __restrict__ W,
                                                       const float* __restrict__ WWm,
                                                       const float* __restrict__ biasN,
                                                       const float* __restrict__ xwc,
                                                       const float* __restrict__ ln1w,
                                                       const float* __restrict__ ln1b,
                                                       const float* __restrict__ ln2w,
                                                       const float* __restrict__ ln2b,
                                                       float* __restrict__ out) {
  const int n = blockIdx.x;
  __shared__ __align__(16) float Wn[3072];
  __shared__ __align__(16) float WWn[512];
  __shared__ __align__(16) float x0v[512], y1v[512], y2v[512];
  __shared__ __align__(16) float xwv[256];
  __shared__ __align__(16) float bv[64];
  const int tid = threadIdx.x;
  for (int i = tid; i < 768; i += 256)
    *(float4*)&Wn[i << 2] = *(const float4*)(W + (size_t)n * 3072 + (i << 2));
  if (tid < 128) {
    *(float4*)&WWn[tid << 2] = *(const float4*)(WWm + (size_t)n * 512 + (tid << 2));
    *(float4*)&y1v[tid << 2] = *(const float4*)(Y1 + (size_t)n * 512 + (tid << 2));
    *(float4*)&y2v[tid << 2] = *(const float4*)(Y2 + (size_t)n * 512 + (tid << 2));
    const int b = tid >> 3, c4 = (tid & 7) << 2;
    *(float4*)&x0v[(b << 5) + c4] = *(const float4*)(x + ((size_t)b * NN + n) * DINC + c4);
  }
  if (tid < 64) {
    const int b = tid >> 2, i4 = (tid & 3) << 2;
    *(float4*)&xwv[(b << 4) + i4] = *(const float4*)(xwc + ((size_t)b * NN + n) * 16 + i4);
  }
  if (tid < 16)
    *(float4*)&bv[tid << 2] = *(const float4*)(biasN + (size_t)n * 64 + (tid << 2));
  __syncthreads();
  const int o = tid & 31, bg = tid >> 5;
  const float w1 = ln1w[o], b1 = ln1b[o], w2 = ln2w[o], b2 = ln2b[o];
  const float bvg = bv[o], bvw = bv[32 + o];
#pragma unroll
  for (int rep = 0; rep < 2; ++rep) {
    const int b = bg + (rep << 3);
    float gv = 0.f;
#pragma unroll
    for (int i = 0; i < 32; ++i) gv = fmaf(x0v[(b << 5) + i], Wn[i * 32 + o], gv);
#pragma unroll
    for (int i = 0; i < 32; ++i) gv = fmaf(y1v[(b << 5) + i], Wn[1024 + i * 32 + o], gv);
#pragma unroll
    for (int i = 0; i < 32; ++i) gv = fmaf(y2v[(b << 5) + i], Wn[2048 + i * 32 + o], gv);
    float wv = 0.f;
#pragma unroll
    for (int i = 0; i < 16; ++i) wv = fmaf(xwv[(b << 4) + i], WWn[i * 32 + o], wv);
    float s1 = gv, s2 = gv * gv;
#pragma unroll
    for (int m = 16; m >= 1; m >>= 1) { s1 += __shfl_xor(s1, m, 32); s2 += __shfl_xor(s2, m, 32); }
    const float mu = s1 * 0.03125f;
    const float var = s2 * 0.03125f - mu * mu;
    const float og = (gv - mu) * rsqrtf(var + 1e-5f) * w1 + b1 + bvg;
    float t1 = wv, t2 = wv * wv;
#pragma unroll
    for (int m = 16; m >= 1; m >>= 1) { t1 += __shfl_xor(t1, m, 32); t2 += __shfl_xor(t2, m, 32); }
    const float mu2 = t1 * 0.03125f;
    const float var2 = t2 * 0.03125f - mu2 * mu2;
    const float ow = (wv - mu2) * rsqrtf(var2 + 1e-5f) * w2 + b2 + bvw;
    float* op = out + ((size_t)b * NN + n) * 64;
    op[o] = og;
    op[32 + o] = ow;
  }
}

// ---------------------------------------------------------------------------
// Workspace map (fp32 elements), high-water 30,181,440 floats = 120.7 MB:
//   [0, 25M)             A fp32 -> P bf16 (ldp=10000 ushort; first 5120 = P+pad)
//                        + split-K partials in each row's free half
//                          (floats m*5000 + 2564 + z*512 .. +512)
//                        -> after reduce2: overlaid by Wm/WWm/biasN/xwc
//   [25.0M, 26.31072M)   XbT bf16 [512][5120]   (dead after GEMM1)
//   [26.31072M,27.62144M) Y1t bf16 [512][5120]  (dead after GEMM2)
//   [25.0M, 27.56M)      Y2f fp32 (written by reduce2, overlays XbT+Y1t)
//   [27.62144M,30.18144M) Y1f fp32
// ---------------------------------------------------------------------------
extern "C" void kernel_launch(void* const* d_in, const int* in_sizes, int n_in,
                              void* d_out, int out_size, void* d_ws, size_t ws_size,
                              hipStream_t stream) {
  const float* x     = (const float*)d_in[0];
  const float* xwin  = (const float*)d_in[1];
  const float* emb   = (const float*)d_in[2];
  const float* wpool = (const float*)d_in[3];
  const float* wwin  = (const float*)d_in[4];
  const float* bpool = (const float*)d_in[5];
  const float* T     = (const float*)d_in[6];
  const float* ln1w  = (const float*)d_in[7];
  const float* ln1b  = (const float*)d_in[8];
  const float* ln2w  = (const float*)d_in[9];
  const float* ln2b  = (const float*)d_in[10];
  float* out = (float*)d_out;
  float* ws = (float*)d_ws;

  float*  A    = ws;
  ushort* P    = (ushort*)ws;
  ushort* XbT  = (ushort*)(ws + 25000000);
  ushort* Y1t  = (ushort*)(ws + 26310720);
  float*  Y1f  = ws + 27621440;
  float*  Y2f  = ws + 25000000;   // overlays XbT+Y1t (written after GEMM2)
  float*  Wm    = ws;             // overlays P+partials after reduce2
  float*  WWm   = ws + 15360000;
  float*  biasN = ws + 17920000;
  float*  xwc   = ws + 18240000;

  build_A_kernel<<<dim3(79, 79), dim3(16, 16), 0, stream>>>(emb, A);
  convert_P_kernel<<<NN, 256, 0, stream>>>(A);
  transpose_xb_kernel<<<dim3(20, 512), 256, 0, stream>>>(x, XbT);
  mfma_gemm_kernel<<<dim3(4, 40, 4), 256, 0, stream>>>(P, XbT, ws);
  reduce_kernel<<<dim3(8, 80), 256, 0, stream>>>(ws, Y1f, Y1t, 1);
  mfma_gemm_kernel<<<dim3(4, 40, 4), 256, 0, stream>>>(P, Y1t, ws);
  reduce_kernel<<<dim3(8, 80), 256, 0, stream>>>(ws, Y2f, (ushort*)nullptr, 0);
  emb_gemm_kernel<<<dim3(48, 157), 256, 0, stream>>>(emb, wpool, Wm, NN, 3072);
  emb_gemm_kernel<<<dim3(8, 157), 256, 0, stream>>>(emb, wwin, WWm, NN, 512);
  emb_gemm_kernel<<<dim3(1, 157), 256, 0, stream>>>(emb, bpool, biasN, NN, 64);
  window_combine_kernel<<<(BB * NN * 16 + 255) / 256, 256, 0, stream>>>(xwin, T, xwc);
  fuse_out_kernel<<<NN, 256, 0, stream>>>(x, Y1f, Y2f, Wm, WWm, biasN, xwc,
                                          ln1w, ln1b, ln2w, ln2b, out);
}